// Round 3
// baseline (570.461 us; speedup 1.0000x reference)
//
#include <hip/hip_runtime.h>

#define NIMG     4991
#define RIRLEN   3968
#define NTHREADS 1024
#define PAD40    40
#define SRIR     4088        // 40 front pad + 3968 + 80 back pad
#define PI_F     3.14159265358979323846f
#define INV_PI   0.31830988618379067f
#define SR_OVER_C 46.647230320699704f   // 16000 / 343

// ---- compile-time compact image-source table: all (x,y,z), |x|+|y|+|z| <= 15 ----
struct Tab { int v[NIMG]; };
static constexpr Tab make_tab() {
    Tab t{};
    int k = 0;
    for (int x = -15; x <= 15; ++x)
        for (int y = -15; y <= 15; ++y)
            for (int z = -15; z <= 15; ++z) {
                int ax = x < 0 ? -x : x;
                int ay = y < 0 ? -y : y;
                int az = z < 0 ? -z : z;
                if (ax + ay + az <= 15)
                    t.v[k++] = (x + 15) | ((y + 15) << 8) | ((z + 15) << 16);
            }
    return t;
}
__constant__ Tab c_tab = make_tab();

static __device__ __forceinline__ int iabs(int v) { return v < 0 ? -v : v; }

__global__ __launch_bounds__(NTHREADS)
void rir_kernel(const float* __restrict__ inp, float* __restrict__ out, int B) {
    const int b   = blockIdx.x;        // one block per batch element
    const int tid = threadIdx.x;

    __shared__ __align__(16) float s_rir[SRIR];
    __shared__ float2 s_cs[81];        // (cos, sin)(pi*n/40)/... scaled below
    __shared__ float  s_par[12];

    for (int t = tid; t < SRIR; t += NTHREADS) s_rir[t] = 0.0f;
    if (tid < 81) {
        // angle pi*n/40 rad -> n/80 revolutions for v_sin/v_cos
        float rev = (float)(tid - 40) * (1.0f / 80.0f);
        s_cs[tid] = make_float2(__builtin_amdgcn_cosf(rev), __builtin_amdgcn_sinf(rev));
    }
    if (tid == 0) {
        const float* ip = inp + b * 12;
        float rx = ip[0], ry = ip[1], rz = ip[2];
        float mx = ip[3] * rx, my = ip[4] * ry, mz = ip[5] * rz;
        float sx = ip[6] * rx, sy = ip[7] * ry, sz = ip[8] * rz;
        float aw = __builtin_fmaf(ip[9],  0.84f, 0.01f);   // walls x,y (lo+hi)
        float a4 = __builtin_fmaf(ip[10], 0.84f, 0.01f);   // z lo
        float a5 = __builtin_fmaf(ip[11], 0.84f, 0.01f);   // z hi
        s_par[0] = rx; s_par[1] = ry; s_par[2] = rz;
        s_par[3] = mx; s_par[4] = my; s_par[5] = mz;
        s_par[6] = sx; s_par[7] = sy; s_par[8] = sz;
        // log2(tr) = 0.5 * log2(1 - a)
        s_par[9]  = 0.5f * __builtin_amdgcn_logf(1.0f - aw);
        s_par[10] = 0.5f * __builtin_amdgcn_logf(1.0f - a4);
        s_par[11] = 0.5f * __builtin_amdgcn_logf(1.0f - a5);
        float dx = mx - sx, dy = my - sy, dz = mz - sz;
        out[(size_t)B * RIRLEN + b] = __builtin_fmaf(
            __builtin_sqrtf(dx * dx + dy * dy + dz * dz), SR_OVER_C, 40.0f);
    }
    __syncthreads();

    const float rx = s_par[0], ry = s_par[1], rz = s_par[2];
    const float mx = s_par[3], my = s_par[4], mz = s_par[5];
    const float sx = s_par[6], sy = s_par[7], sz = s_par[8];
    const float lw = s_par[9], l4 = s_par[10], l5 = s_par[11];

    for (int i = tid; i < NIMG; i += NTHREADS) {
        const int p = c_tab.v[i];
        const int x = (p & 255) - 15;
        const int y = ((p >> 8) & 255) - 15;
        const int z = ((p >> 16) & 255) - 15;

        // image location per dim: odd -> room*(n+1) - src ; even -> room*n + src
        const float ix = (x & 1) ? __builtin_fmaf(rx, (float)(x + 1), -sx)
                                 : __builtin_fmaf(rx, (float)x, sx);
        const float iy = (y & 1) ? __builtin_fmaf(ry, (float)(y + 1), -sy)
                                 : __builtin_fmaf(ry, (float)y, sy);
        const float iz = (z & 1) ? __builtin_fmaf(rz, (float)(z + 1), -sz)
                                 : __builtin_fmaf(rz, (float)z, sz);

        const float dx = ix - mx, dy = iy - my, dz = iz - mz;
        const float dist  = __builtin_sqrtf(__builtin_fmaf(dx, dx, __builtin_fmaf(dy, dy, dz * dz)));
        const float delay = dist * SR_OVER_C;
        const float di    = __builtin_ceilf(delay);
        const int   ti0   = (int)di - 40;
        if (ti0 >= RIRLEN) continue;   // whole window beyond RIR -> dropped

        // att = prod tr^exp  ==  exp2( sum e * log2(tr) )
        const int ew = iabs(x >> 1) + iabs((x + 1) >> 1) + iabs(y >> 1) + iabs((y + 1) >> 1);
        const float att = __builtin_amdgcn_exp2f(__builtin_fmaf((float)ew, lw,
                              __builtin_fmaf((float)iabs(z >> 1), l4,
                                   (float)iabs((z + 1) >> 1) * l5)));
        const float amp = att / dist;

        float frac = di - delay;                     // in [0,1)
        frac = frac < 1e-10f ? 1e-10f : frac;        // center-tap safe: c1*rcp(xv) -> amp
        // sin(pi*frac): pi*frac rad = frac/2 rev
        const float c1 = amp * __builtin_amdgcn_sinf(0.5f * frac) * INV_PI;
        // hann angle pi*frac/40 rad = frac/80 rev
        const float ca = 0.5f * __builtin_amdgcn_cosf(frac * (1.0f / 80.0f));
        const float sa = 0.5f * __builtin_amdgcn_sinf(frac * (1.0f / 80.0f));

        float* base = &s_rir[PAD40 + ti0];   // ti0 >= -40 always; ti0 <= 3967 here
        float nf  = -40.0f;
        float c1a = c1;                      // sign (+) at n=-40 (even)
        #pragma unroll 8
        for (int j = 0; j < 80; ++j) {
            const float2 cs = s_cs[j];                                   // LDS broadcast
            const float  h  = __builtin_fmaf(ca, cs.x, 0.5f) - sa * cs.y; // hann(x)
            const float  xv = frac + nf;
            const float  v  = (c1a * __builtin_amdgcn_rcpf(xv)) * h;
            atomicAdd(&base[j], v);          // unconditional: buffer padded both ends
            nf += 1.0f;
            c1a = -c1a;
        }
    }
    __syncthreads();

    // plain coalesced float4 stores — no global atomics
    const float4* src4 = (const float4*)&s_rir[PAD40];
    float4* dst4 = (float4*)(out + (size_t)b * RIRLEN);
    for (int t = tid; t < RIRLEN / 4; t += NTHREADS) dst4[t] = src4[t];
}

extern "C" void kernel_launch(void* const* d_in, const int* in_sizes, int n_in,
                              void* d_out, int out_size, void* d_ws, size_t ws_size,
                              hipStream_t stream) {
    const float* inp = (const float*)d_in[0];
    float* out = (float*)d_out;
    const int B = in_sizes[0] / 12;
    rir_kernel<<<dim3(B), dim3(NTHREADS), 0, stream>>>(inp, out, B);
}

// Round 5
// 565.961 us; speedup vs baseline: 1.0080x; 1.0080x over previous
//
#include <hip/hip_runtime.h>

#define NIMG     4991
#define RIRLEN   3968
#define NTHREADS 1024
#define PAD40    40
#define SRIR     4088        // 40 front pad + 3968 + 80 back pad
#define PI_F     3.14159265358979323846f
#define INV_PI   0.31830988618379067f
#define SR_OVER_C 46.647230320699704f   // 16000 / 343
// rotation by pi/40 radians per tap
#define C0 0.9969173337331280f
#define S0 0.0784590957278449f

// ---- compile-time compact image-source table: all (x,y,z), |x|+|y|+|z| <= 15 ----
struct Tab { int v[NIMG]; };
static constexpr Tab make_tab() {
    Tab t{};
    int k = 0;
    for (int x = -15; x <= 15; ++x)
        for (int y = -15; y <= 15; ++y)
            for (int z = -15; z <= 15; ++z) {
                int ax = x < 0 ? -x : x;
                int ay = y < 0 ? -y : y;
                int az = z < 0 ? -z : z;
                if (ax + ay + az <= 15)
                    t.v[k++] = (x + 15) | ((y + 15) << 8) | ((z + 15) << 16);
            }
    return t;
}
__constant__ Tab c_tab = make_tab();

static __device__ __forceinline__ int iabs(int v) { return v < 0 ? -v : v; }

typedef __attribute__((address_space(3))) float lds_float;

// native non-returning LDS float atomic add (compiler CAS-expands atomicAdd
// on shared f32 under default denormal mode -- ~200cy/tap; this is ~4cy)
static __device__ __forceinline__ void lds_fadd(unsigned addr, float v) {
    __asm__ volatile("ds_add_f32 %0, %1" :: "v"(addr), "v"(v) : "memory");
}
static __device__ __forceinline__ void lds_fadd_off4(unsigned addr, float v) {
    __asm__ volatile("ds_add_f32 %0, %1 offset:4" :: "v"(addr), "v"(v) : "memory");
}

__global__ __launch_bounds__(NTHREADS)
void rir_kernel(const float* __restrict__ inp, float* __restrict__ out, int B) {
    const int b   = blockIdx.x;        // one block per batch element
    const int tid = threadIdx.x;

    __shared__ __align__(16) float s_rir[SRIR];
    __shared__ float  s_par[12];

    for (int t = tid; t < SRIR; t += NTHREADS) s_rir[t] = 0.0f;
    if (tid == 0) {
        const float* ip = inp + b * 12;
        float rx = ip[0], ry = ip[1], rz = ip[2];
        float mx = ip[3] * rx, my = ip[4] * ry, mz = ip[5] * rz;
        float sx = ip[6] * rx, sy = ip[7] * ry, sz = ip[8] * rz;
        float aw = __builtin_fmaf(ip[9],  0.84f, 0.01f);   // walls x,y (lo+hi)
        float a4 = __builtin_fmaf(ip[10], 0.84f, 0.01f);   // z lo
        float a5 = __builtin_fmaf(ip[11], 0.84f, 0.01f);   // z hi
        s_par[0] = rx; s_par[1] = ry; s_par[2] = rz;
        s_par[3] = mx; s_par[4] = my; s_par[5] = mz;
        s_par[6] = sx; s_par[7] = sy; s_par[8] = sz;
        // log2(tr) = 0.5 * log2(1 - a)
        s_par[9]  = 0.5f * __builtin_amdgcn_logf(1.0f - aw);
        s_par[10] = 0.5f * __builtin_amdgcn_logf(1.0f - a4);
        s_par[11] = 0.5f * __builtin_amdgcn_logf(1.0f - a5);
        float dx = mx - sx, dy = my - sy, dz = mz - sz;
        out[(size_t)B * RIRLEN + b] = __builtin_fmaf(
            __builtin_sqrtf(dx * dx + dy * dy + dz * dz), SR_OVER_C, 40.0f);
    }
    __syncthreads();

    const float rx = s_par[0], ry = s_par[1], rz = s_par[2];
    const float mx = s_par[3], my = s_par[4], mz = s_par[5];
    const float sx = s_par[6], sy = s_par[7], sz = s_par[8];
    const float lw = s_par[9], l4 = s_par[10], l5 = s_par[11];

    for (int i = tid; i < NIMG; i += NTHREADS) {
        const int p = c_tab.v[i];
        const int x = (p & 255) - 15;
        const int y = ((p >> 8) & 255) - 15;
        const int z = ((p >> 16) & 255) - 15;

        // image location per dim: odd -> room*(n+1) - src ; even -> room*n + src
        const float ix = (x & 1) ? __builtin_fmaf(rx, (float)(x + 1), -sx)
                                 : __builtin_fmaf(rx, (float)x, sx);
        const float iy = (y & 1) ? __builtin_fmaf(ry, (float)(y + 1), -sy)
                                 : __builtin_fmaf(ry, (float)y, sy);
        const float iz = (z & 1) ? __builtin_fmaf(rz, (float)(z + 1), -sz)
                                 : __builtin_fmaf(rz, (float)z, sz);

        const float dx = ix - mx, dy = iy - my, dz = iz - mz;
        const float dist  = __builtin_sqrtf(__builtin_fmaf(dx, dx, __builtin_fmaf(dy, dy, dz * dz)));
        const float delay = dist * SR_OVER_C;
        const float di    = __builtin_ceilf(delay);
        const int   ti0   = (int)di - 40;
        if (ti0 >= RIRLEN) continue;   // whole window beyond RIR -> dropped

        // att = prod tr^exp  ==  exp2( sum e * log2(tr) )
        const int ew = iabs(x >> 1) + iabs((x + 1) >> 1) + iabs(y >> 1) + iabs((y + 1) >> 1);
        const float att = __builtin_amdgcn_exp2f(__builtin_fmaf((float)ew, lw,
                              __builtin_fmaf((float)iabs(z >> 1), l4,
                                   (float)iabs((z + 1) >> 1) * l5)));
        const float amp = att / dist;

        float frac = di - delay;                     // exact (Sterbenz), in [0,1)
        // clamp so the center tap (xv = frac) gives c1*rcp(frac) -> amp, never inf.
        // 2^-14 sample shift is ~1e-5 of a sample -- far below tolerance.
        frac = frac < 6.103515625e-5f ? 6.103515625e-5f : frac;
        // c1 = amp * sin(pi*frac)/pi ; sinc sign alternates with tap parity
        const float c1p = amp * __builtin_amdgcn_sinf(0.5f * frac) * INV_PI;
        const float c1n = -c1p;
        // hann: h_j = 0.5 + 0.5*cos(pi*(frac + n_j)/40), n_j = j-40.
        // maintain (c,s)=(cos,sin) of theta_j, rotated by pi/40 per tap.
        // theta_0 = pi*frac/40 - pi  ->  c = -cos(pi*frac/40), s = -sin(pi*frac/40)
        float hc = -__builtin_amdgcn_cosf(frac * (1.0f / 80.0f));
        float hs = -__builtin_amdgcn_sinf(frac * (1.0f / 80.0f));

        unsigned a = (unsigned)(unsigned long long)(lds_float*)&s_rir[PAD40 + ti0];
        float nf = -40.0f;   // exact integer float; xv = frac + nf is computed fresh
        #pragma unroll 8
        for (int j = 0; j < 80; j += 2) {
            // tap j (even n -> +):
            float h0 = __builtin_fmaf(0.5f, hc, 0.5f);
            float v0 = (c1p * __builtin_amdgcn_rcpf(frac + nf)) * h0;
            lds_fadd(a, v0);
            float hc1 = __builtin_fmaf(hc, C0, -(hs * S0));
            float hs1 = __builtin_fmaf(hs, C0,  (hc * S0));
            // tap j+1 (odd n -> -):
            float h1 = __builtin_fmaf(0.5f, hc1, 0.5f);
            float v1 = (c1n * __builtin_amdgcn_rcpf(frac + (nf + 1.0f))) * h1;
            lds_fadd_off4(a, v1);
            hc = __builtin_fmaf(hc1, C0, -(hs1 * S0));
            hs = __builtin_fmaf(hs1, C0,  (hc1 * S0));
            nf += 2.0f;
            a  += 8;
        }
    }
    __syncthreads();

    // plain coalesced float4 stores — no global atomics
    const float4* src4 = (const float4*)&s_rir[PAD40];
    float4* dst4 = (float4*)(out + (size_t)b * RIRLEN);
    for (int t = tid; t < RIRLEN / 4; t += NTHREADS) dst4[t] = src4[t];
}

extern "C" void kernel_launch(void* const* d_in, const int* in_sizes, int n_in,
                              void* d_out, int out_size, void* d_ws, size_t ws_size,
                              hipStream_t stream) {
    const float* inp = (const float*)d_in[0];
    float* out = (float*)d_out;
    const int B = in_sizes[0] / 12;
    rir_kernel<<<dim3(B), dim3(NTHREADS), 0, stream>>>(inp, out, B);
}

// Round 6
// 465.950 us; speedup vs baseline: 1.2243x; 1.2146x over previous
//
#include <hip/hip_runtime.h>

#define NIMG     4991
#define RIRLEN   3968
#define NTHREADS 512
#define NWAVES   8
#define PAD40    40
#define SRIR     4088        // per-wave buffer: 40 front pad + 3968 + 80 back pad
#define NCLAIM   1024
#define INV_PI   0.31830988618379067f
#define SR_OVER_C 46.647230320699704f   // 16000 / 343
#define KREC     1.9938346674662560f    // 2*cos(pi/40)

// ---- compile-time compact image-source table: all (x,y,z), |x|+|y|+|z| <= 15 ----
struct Tab { int v[NIMG]; };
static constexpr Tab make_tab() {
    Tab t{};
    int k = 0;
    for (int x = -15; x <= 15; ++x)
        for (int y = -15; y <= 15; ++y)
            for (int z = -15; z <= 15; ++z) {
                int ax = x < 0 ? -x : x;
                int ay = y < 0 ? -y : y;
                int az = z < 0 ? -z : z;
                if (ax + ay + az <= 15)
                    t.v[k++] = (x + 15) | ((y + 15) << 8) | ((z + 15) << 16);
            }
    return t;
}
__constant__ Tab c_tab = make_tab();

static __device__ __forceinline__ int iabs(int v) { return v < 0 ? -v : v; }

typedef __attribute__((address_space(3))) float lds_float;
typedef float v4f __attribute__((ext_vector_type(4)));

__global__ __launch_bounds__(NTHREADS)
void rir_kernel(const float* __restrict__ inp, float* __restrict__ out, int B) {
    const int b   = blockIdx.x;        // one block per batch element
    const int tid = threadIdx.x;
    const int wv  = tid >> 6;          // wave id 0..7

    __shared__ __align__(16) float s_bufs[NWAVES * SRIR];   // per-wave private RIR
    __shared__ int   s_claim[NCLAIM];                       // anchor-claim tags
    __shared__ float s_par[12];

    v4f* z4 = (v4f*)s_bufs;
    for (int t = tid; t < (NWAVES * SRIR) / 4; t += NTHREADS) z4[t] = (v4f)0.0f;
    if (tid == 0) {
        const float* ip = inp + b * 12;
        float rx = ip[0], ry = ip[1], rz = ip[2];
        float mx = ip[3] * rx, my = ip[4] * ry, mz = ip[5] * rz;
        float sx = ip[6] * rx, sy = ip[7] * ry, sz = ip[8] * rz;
        float aw = __builtin_fmaf(ip[9],  0.84f, 0.01f);   // walls x,y (lo+hi)
        float a4 = __builtin_fmaf(ip[10], 0.84f, 0.01f);   // z lo
        float a5 = __builtin_fmaf(ip[11], 0.84f, 0.01f);   // z hi
        s_par[0] = rx; s_par[1] = ry; s_par[2] = rz;
        s_par[3] = mx; s_par[4] = my; s_par[5] = mz;
        s_par[6] = sx; s_par[7] = sy; s_par[8] = sz;
        s_par[9]  = 0.5f * __builtin_amdgcn_logf(1.0f - aw);   // log2(tr)
        s_par[10] = 0.5f * __builtin_amdgcn_logf(1.0f - a4);
        s_par[11] = 0.5f * __builtin_amdgcn_logf(1.0f - a5);
        float dx = mx - sx, dy = my - sy, dz = mz - sz;
        out[(size_t)B * RIRLEN + b] = __builtin_fmaf(
            __builtin_sqrtf(dx * dx + dy * dy + dz * dz), SR_OVER_C, 40.0f);
    }
    __syncthreads();

    const float rx = s_par[0], ry = s_par[1], rz = s_par[2];
    const float mx = s_par[3], my = s_par[4], mz = s_par[5];
    const float sx = s_par[6], sy = s_par[7], sz = s_par[8];
    const float lw = s_par[9], l4 = s_par[10], l5 = s_par[11];

    volatile int* vc = s_claim;

    for (int i = tid; i < NIMG; i += NTHREADS) {
        const int p = c_tab.v[i];
        const int x = (p & 255) - 15;
        const int y = ((p >> 8) & 255) - 15;
        const int z = ((p >> 16) & 255) - 15;

        const float ix = (x & 1) ? __builtin_fmaf(rx, (float)(x + 1), -sx)
                                 : __builtin_fmaf(rx, (float)x, sx);
        const float iy = (y & 1) ? __builtin_fmaf(ry, (float)(y + 1), -sy)
                                 : __builtin_fmaf(ry, (float)y, sy);
        const float iz = (z & 1) ? __builtin_fmaf(rz, (float)(z + 1), -sz)
                                 : __builtin_fmaf(rz, (float)z, sz);

        const float dx = ix - mx, dy = iy - my, dz = iz - mz;
        const float dist  = __builtin_sqrtf(__builtin_fmaf(dx, dx, __builtin_fmaf(dy, dy, dz * dz)));
        const float delay = dist * SR_OVER_C;
        const float di    = __builtin_ceilf(delay);
        const int   ti0   = (int)di - 40;
        if (ti0 >= RIRLEN) continue;   // whole window beyond RIR -> dropped

        const int ew = iabs(x >> 1) + iabs((x + 1) >> 1) + iabs(y >> 1) + iabs((y + 1) >> 1);
        const float att = __builtin_amdgcn_exp2f(__builtin_fmaf((float)ew, lw,
                              __builtin_fmaf((float)iabs(z >> 1), l4,
                                   (float)iabs((z + 1) >> 1) * l5)));
        const float amp = att / dist;

        float frac = di - delay;                     // in [0,1)
        frac = frac < 6.103515625e-5f ? 6.103515625e-5f : frac;  // center-tap safe

        const int s    = ti0 & 3;
        const int tq   = ti0 - s;                    // quad-aligned anchor
        const int slot = (tq + 40) >> 2;             // 0..1001

        // ---- claim protocol: detect in-wave duplicate anchors (exact) ----
        vc[slot] = tid;
        int r1 = vc[slot];
        bool bad = (r1 != tid);
        if (__any(bad)) {
            if (bad) vc[slot] = tid;     // losers protest so winners see the clash
            int r2 = vc[slot];
            bad = bad || (r2 != tid);
        }

        // ---- tap math setup ----
        const float c1p = amp * __builtin_amdgcn_sinf(0.5f * frac) * INV_PI;
        const float c1a = (s & 1) ? -c1p : c1p;      // sign at quad start = (-1)^s
        const float x0  = frac - (float)(40 + s);    // x at first padded tap
        // Chebyshev recurrence for cos(pi*x_k/40): c_{k+1} = K*c_k - c_{k-1}
        float cc = __builtin_amdgcn_cosf(x0 * (1.0f / 80.0f));          // rev units
        float cp = __builtin_amdgcn_cosf((x0 - 1.0f) * (1.0f / 80.0f));

        unsigned a = (unsigned)(unsigned long long)(lds_float*)
                     &s_bufs[wv * SRIR + PAD40 + tq];   // 16B-aligned

        if (!bad) {
            float xq = x0;
            #pragma unroll
            for (int k = 0; k < 21; ++k) {
                v4f rv;
                __asm__ volatile("ds_read_b128 %0, %1\n\ts_waitcnt lgkmcnt(0)"
                                 : "=v"(rv) : "v"(a) : "memory");
                {   float xx = xq;
                    float h  = __builtin_fmaf(0.5f, cc, 0.5f);
                    float v  = (c1a * __builtin_amdgcn_rcpf(xx)) * h;
                    rv.x += (__builtin_fabsf(xx) < 40.0f) ? v : 0.0f;
                    float cn = __builtin_fmaf(KREC, cc, -cp); cp = cc; cc = cn; }
                {   float xx = xq + 1.0f;
                    float h  = __builtin_fmaf(0.5f, cc, 0.5f);
                    float v  = (c1a * __builtin_amdgcn_rcpf(xx)) * h;
                    rv.y -= (__builtin_fabsf(xx) < 40.0f) ? v : 0.0f;
                    float cn = __builtin_fmaf(KREC, cc, -cp); cp = cc; cc = cn; }
                {   float xx = xq + 2.0f;
                    float h  = __builtin_fmaf(0.5f, cc, 0.5f);
                    float v  = (c1a * __builtin_amdgcn_rcpf(xx)) * h;
                    rv.z += (__builtin_fabsf(xx) < 40.0f) ? v : 0.0f;
                    float cn = __builtin_fmaf(KREC, cc, -cp); cp = cc; cc = cn; }
                {   float xx = xq + 3.0f;
                    float h  = __builtin_fmaf(0.5f, cc, 0.5f);
                    float v  = (c1a * __builtin_amdgcn_rcpf(xx)) * h;
                    rv.w -= (__builtin_fabsf(xx) < 40.0f) ? v : 0.0f;
                    float cn = __builtin_fmaf(KREC, cc, -cp); cp = cc; cc = cn; }
                __asm__ volatile("ds_write_b128 %0, %1" :: "v"(a), "v"(rv) : "memory");
                a  += 16;
                xq += 4.0f;
            }
        }
        if (bad) {
            // rare: duplicate anchor within wave -> native LDS atomic fallback
            float xq = x0;
            #pragma unroll 3
            for (int k = 0; k < 21; ++k) {
                float xx = xq;
                float h  = __builtin_fmaf(0.5f, cc, 0.5f);
                float v  = (c1a * __builtin_amdgcn_rcpf(xx)) * h;
                float v0 = (__builtin_fabsf(xx) < 40.0f) ? v : 0.0f;
                float cn = __builtin_fmaf(KREC, cc, -cp); cp = cc; cc = cn;
                xx = xq + 1.0f;
                h  = __builtin_fmaf(0.5f, cc, 0.5f);
                v  = (c1a * __builtin_amdgcn_rcpf(xx)) * h;
                float v1 = (__builtin_fabsf(xx) < 40.0f) ? -v : 0.0f;
                cn = __builtin_fmaf(KREC, cc, -cp); cp = cc; cc = cn;
                xx = xq + 2.0f;
                h  = __builtin_fmaf(0.5f, cc, 0.5f);
                v  = (c1a * __builtin_amdgcn_rcpf(xx)) * h;
                float v2 = (__builtin_fabsf(xx) < 40.0f) ? v : 0.0f;
                cn = __builtin_fmaf(KREC, cc, -cp); cp = cc; cc = cn;
                xx = xq + 3.0f;
                h  = __builtin_fmaf(0.5f, cc, 0.5f);
                v  = (c1a * __builtin_amdgcn_rcpf(xx)) * h;
                float v3 = (__builtin_fabsf(xx) < 40.0f) ? -v : 0.0f;
                cn = __builtin_fmaf(KREC, cc, -cp); cp = cc; cc = cn;
                __asm__ volatile("ds_add_f32 %0, %1"           :: "v"(a), "v"(v0) : "memory");
                __asm__ volatile("ds_add_f32 %0, %1 offset:4"  :: "v"(a), "v"(v1) : "memory");
                __asm__ volatile("ds_add_f32 %0, %1 offset:8"  :: "v"(a), "v"(v2) : "memory");
                __asm__ volatile("ds_add_f32 %0, %1 offset:12" :: "v"(a), "v"(v3) : "memory");
                a  += 16;
                xq += 4.0f;
            }
        }
    }
    __syncthreads();

    // epilogue: sum the 8 wave-private buffers, plain coalesced stores
    const v4f* s4 = (const v4f*)s_bufs;
    v4f* dst4 = (v4f*)(out + (size_t)b * RIRLEN);
    for (int t = tid; t < RIRLEN / 4; t += NTHREADS) {
        v4f acc = s4[(PAD40 / 4) + t];
        #pragma unroll
        for (int w = 1; w < NWAVES; ++w)
            acc += s4[(w * SRIR + PAD40) / 4 + t];
        dst4[t] = acc;
    }
}

extern "C" void kernel_launch(void* const* d_in, const int* in_sizes, int n_in,
                              void* d_out, int out_size, void* d_ws, size_t ws_size,
                              hipStream_t stream) {
    const float* inp = (const float*)d_in[0];
    float* out = (float*)d_out;
    const int B = in_sizes[0] / 12;
    rir_kernel<<<dim3(B), dim3(NTHREADS), 0, stream>>>(inp, out, B);
}